// Round 6
// baseline (984.181 us; speedup 1.0000x reference)
//
#include <hip/hip_runtime.h>
#include <stdint.h>

typedef unsigned short u16;
typedef unsigned long long u64;
typedef __bf16 bf16x8 __attribute__((ext_vector_type(8)));
typedef float f32x4 __attribute__((ext_vector_type(4)));

#define NB 4
#define NS 2048
#define NC 256
#define NH 8
#define NM (NB*NS)        // 8192 rows (b,s)
#define NQKV (3*NH*NC)    // 6144
#define NHC (NH*NC)       // 2048

__device__ __forceinline__ u16 f2b(float f) {
  uint32_t u = __builtin_bit_cast(uint32_t, f);
  u += 0x7FFFu + ((u >> 16) & 1u);   // RNE
  return (u16)(u >> 16);
}
__device__ __forceinline__ float b2f(u16 h) {
  uint32_t u = ((uint32_t)h) << 16;
  return __builtin_bit_cast(float, u);
}
__device__ __forceinline__ void gl_lds16(const void* g, void* s) {
  __builtin_amdgcn_global_load_lds((const __attribute__((address_space(1))) void*)g,
                                   (__attribute__((address_space(3))) void*)s, 16, 0, 0);
}

// ---------------- prep: f32 -> bf16, weight transposes ----------------------
__global__ void prep_kernel(const float* __restrict__ x, const float* __restrict__ Wq,
                            const float* __restrict__ Wk, const float* __restrict__ Wv,
                            const float* __restrict__ Wfc,
                            u16* __restrict__ xb, u16* __restrict__ wt, u16* __restrict__ wfct) {
  const int total = NM*NC + NQKV*NC + NC*NHC;
  for (int i = blockIdx.x*blockDim.x + threadIdx.x; i < total; i += gridDim.x*blockDim.x) {
    if (i < NM*NC) {
      xb[i] = f2b(x[i]);
    } else if (i < NM*NC + NQKV*NC) {
      int j = i - NM*NC;              // j = n*256 + c ; n = proj*2048 + h*256 + d
      int n = j >> 8, c = j & 255;
      int proj = n >> 11, h = (n >> 8) & 7, d = n & 255;
      const float* W = (proj == 0) ? Wq : (proj == 1) ? Wk : Wv;
      wt[j] = f2b(W[((size_t)(h*NC + c))*NC + d]);     // wt[n][c] = W[h][c][d]
    } else {
      int j = i - NM*NC - NQKV*NC;    // j = d*2048 + jj
      int d = j >> 11, jj = j & 2047;
      wfct[j] = f2b(Wfc[(size_t)jj*NC + d]);           // wfct[d][jj] = Wfc[jj][d]
    }
  }
}

// ---------------- fused QKV projection GEMM (head-group aware) --------------
// Row-major scatter to [b,hloc,s,d] for q, k, v.
__global__ void gemm_qkv(const u16* __restrict__ xb, const u16* __restrict__ wt,
                         const float* __restrict__ bq, const float* __restrict__ bk,
                         const float* __restrict__ bv,
                         u16* __restrict__ qo, u16* __restrict__ ko, u16* __restrict__ vo,
                         int h0, int hg, int lg_hg) {
  __shared__ u16 As[128*32];
  __shared__ u16 Bs[128*32];
  const int tid = threadIdx.x;
  const int w = tid >> 6, l = tid & 63;
  const int wr = w >> 1, wc = w & 1;
  const int m0 = blockIdx.x * 128;
  const int n0 = blockIdx.y * 128;             // within group N
  const int proj = n0 >> (8 + lg_hg);          // n0 / (hg*256)
  const int rem  = n0 & ((hg << 8) - 1);
  const int hloc = rem >> 8;
  const int dbase = rem & 255;                 // 0 or 128
  const int wrow0 = proj*2048 + ((h0 + hloc) << 8) + dbase;
  const int arow = tid >> 2;          // 0..63
  const int acol = (tid & 3) * 8;     // elems
  f32x4 acc[4][4] = {};
  for (int k0 = 0; k0 < 256; k0 += 32) {
    __syncthreads();
#pragma unroll
    for (int i = 0; i < 2; i++) {
      gl_lds16(xb + (size_t)(m0 + i*64 + arow)*256 + k0 + acol, (char*)As + i*4096 + w*1024);
      gl_lds16(wt + (size_t)(wrow0 + i*64 + arow)*256 + k0 + acol, (char*)Bs + i*4096 + w*1024);
    }
    __syncthreads();
    bf16x8 af[4], bfr[4];
#pragma unroll
    for (int mt = 0; mt < 4; mt++)
      af[mt] = *(const bf16x8*)&As[(wr*64 + mt*16 + (l&15))*32 + (l>>4)*8];
#pragma unroll
    for (int nt = 0; nt < 4; nt++)
      bfr[nt] = *(const bf16x8*)&Bs[(wc*64 + nt*16 + (l&15))*32 + (l>>4)*8];
#pragma unroll
    for (int mt = 0; mt < 4; mt++)
#pragma unroll
      for (int nt = 0; nt < 4; nt++)
        acc[mt][nt] = __builtin_amdgcn_mfma_f32_16x16x32_bf16(af[mt], bfr[nt], acc[mt][nt], 0, 0, 0);
  }
  // epilogue: +bias, ->bf16, scatter to [B,hg,S,D] (group-local)
  const float* bias = (proj == 0) ? bq : (proj == 1) ? bk : bv;
  u16* dst = (proj == 0) ? qo : (proj == 1) ? ko : vo;
#pragma unroll
  for (int mt = 0; mt < 4; mt++) {
#pragma unroll
    for (int nt = 0; nt < 4; nt++) {
      const int dd = dbase + wc*64 + nt*16 + (l & 15);
      const float bb_ = bias[((h0 + hloc) << 8) + dd];
#pragma unroll
      for (int j = 0; j < 4; j++) {
        const int m = m0 + wr*64 + mt*16 + ((l>>4)<<2) + j;
        const int b = m >> 11, s = m & 2047;
        dst[((size_t)((b*hg + hloc)*2048 + s))*256 + dd] = f2b(acc[mt][nt][j] + bb_);
      }
    }
  }
}

// ---------------- flash attention (16 q/wave, K-frags from global L2) -------
// Round-2 structure, but K never touches LDS: QK^T B-fragments are 16B
// contiguous global loads (L2-resident, separate pipe from LDS). V staged in
// LDS transposed+swizzled (round 2). LDS = 41 KB -> 3 blocks/CU (12 waves).
__global__ void __launch_bounds__(256, 3)
attn_kernel(const u16* __restrict__ q, const u16* __restrict__ k,
            const u16* __restrict__ v, u16* __restrict__ cat,
            int h0, int hg, int lg_hg) {
  __shared__ u16 Vts[256*64];
  __shared__ u16 Ps[4][16*72];       // per-wave P scratch, pad 72 for bank spread
  const int tid = threadIdx.x;
  const int w = tid >> 6, l = tid & 63;
  const int l15 = l & 15, l16 = l >> 4, l7 = l & 7, l8 = l >> 3;
  const int bh = blockIdx.y;                   // b*hg + hloc
  const int b = bh >> lg_hg, hloc = bh & (hg - 1);
  const int q0 = blockIdx.x * 64;
  const u16* qp = q + (size_t)bh * NS * 256;
  const u16* kp = k + (size_t)bh * NS * 256;
  const u16* vp = v + (size_t)bh * NS * 256;

  // Q in registers: rows q0 + w*16 + l15, d = l16*8 + 32c
  bf16x8 qf[8];
  {
    const u16* qr = qp + (size_t)(q0 + w*16 + l15)*256 + l16*8;
#pragma unroll
    for (int c = 0; c < 8; c++) qf[c] = *(const bf16x8*)(qr + c*32);
  }
  f32x4 o[16];
#pragma unroll
  for (int i = 0; i < 16; i++) o[i] = f32x4{0.f, 0.f, 0.f, 0.f};
  float mrow[4], lsum[4];
#pragma unroll
  for (int r = 0; r < 4; r++) { mrow[r] = -1e30f; lsum[r] = 0.f; }
  const float sc = 0.0625f * 1.4426950408889634f;   // 1/sqrt(256) * log2(e)

  // stage V tile kt: transpose into Vts[d][t], granule-swizzled
  auto stageV = [&](int kt) {
#pragma unroll
    for (int i = 0; i < 8; i++) {
      const int d0 = (w + 4*i) * 8;
      uint4 val = *(const uint4*)(vp + (size_t)(kt*64 + l)*256 + d0);
      uint32_t words[4] = {val.x, val.y, val.z, val.w};
#pragma unroll
      for (int j = 0; j < 8; j++) {
        const u16 e = (u16)(words[j >> 1] >> ((j & 1) * 16));
        const int d = d0 + j;
        Vts[d*64 + ((l8 ^ (d & 7)) * 8) + l7] = e;
      }
    }
  };

  stageV(0);
  __syncthreads();

  for (int kt = 0; kt < NS/64; kt++) {
    // QK^T: B-frags straight from global (L2). sacc[tt] = S[q=l16*4+r][t=l15+16tt]
    f32x4 sacc[4];
#pragma unroll
    for (int tt = 0; tt < 4; tt++) sacc[tt] = f32x4{0.f, 0.f, 0.f, 0.f};
    const u16* kb = kp + ((size_t)kt*64 + l15)*256 + l16*8;
    __builtin_amdgcn_s_setprio(1);
#pragma unroll
    for (int ks = 0; ks < 8; ks++) {
      bf16x8 kf[4];
#pragma unroll
      for (int tt = 0; tt < 4; tt++)
        kf[tt] = *(const bf16x8*)(kb + tt*4096 + ks*32);
#pragma unroll
      for (int tt = 0; tt < 4; tt++)
        sacc[tt] = __builtin_amdgcn_mfma_f32_16x16x32_bf16(qf[ks], kf[tt], sacc[tt], 0, 0, 0);
    }
    __builtin_amdgcn_s_setprio(0);

    // online softmax (base-2), defer-max THR=8 (r3/r4-validated)
    float pm[4];
#pragma unroll
    for (int r = 0; r < 4; r++)
      pm[r] = fmaxf(fmaxf(sacc[0][r], sacc[1][r]), fmaxf(sacc[2][r], sacc[3][r])) * sc;
#pragma unroll
    for (int mof = 1; mof <= 8; mof <<= 1)
#pragma unroll
      for (int r = 0; r < 4; r++)
        pm[r] = fmaxf(pm[r], __shfl_xor(pm[r], mof));
    float dm = -1e30f;
#pragma unroll
    for (int r = 0; r < 4; r++) dm = fmaxf(dm, pm[r] - mrow[r]);
    const bool upd = !__all(dm <= 8.0f);
    float fr[4];
    if (upd) {
#pragma unroll
      for (int r = 0; r < 4; r++) {
        const float mn = fmaxf(mrow[r], pm[r]);
        fr[r] = exp2f(mrow[r] - mn);
        mrow[r] = mn;
      }
    }
    float ps[4] = {0.f, 0.f, 0.f, 0.f};
#pragma unroll
    for (int tt = 0; tt < 4; tt++) {
#pragma unroll
      for (int r = 0; r < 4; r++) {
        const float p = exp2f(sacc[tt][r]*sc - mrow[r]);
        const u16 pb = f2b(p);
        ps[r] += b2f(pb);                 // sum what PV will actually use
        Ps[w][(l16*4 + r)*72 + l15 + 16*tt] = pb;
      }
    }
#pragma unroll
    for (int mof = 1; mof <= 8; mof <<= 1)
#pragma unroll
      for (int r = 0; r < 4; r++)
        ps[r] += __shfl_xor(ps[r], mof);
    if (upd) {
#pragma unroll
      for (int r = 0; r < 4; r++) lsum[r] = lsum[r]*fr[r] + ps[r];
#pragma unroll
      for (int dt = 0; dt < 16; dt++)
#pragma unroll
        for (int r = 0; r < 4; r++) o[dt][r] *= fr[r];
    } else {
#pragma unroll
      for (int r = 0; r < 4; r++) lsum[r] += ps[r];
    }

    // PV: o[dt] += P(16x64) * V^T-tile (LDS)
    __builtin_amdgcn_s_setprio(1);
    bf16x8 pa[2];
#pragma unroll
    for (int kk = 0; kk < 2; kk++)
      pa[kk] = *(const bf16x8*)&Ps[w][l15*72 + kk*32 + l16*8];
#pragma unroll
    for (int dt = 0; dt < 16; dt++) {
      const int dr = dt*16 + l15;
#pragma unroll
      for (int kk = 0; kk < 2; kk++) {
        const bf16x8 vf = *(const bf16x8*)&Vts[dr*64 + (((kk*4 + l16) ^ (dr & 7)) << 3)];
        o[dt] = __builtin_amdgcn_mfma_f32_16x16x32_bf16(pa[kk], vf, o[dt], 0, 0, 0);
      }
    }
    __builtin_amdgcn_s_setprio(0);

    __syncthreads();                  // PV done everywhere; Vts dead
    if (kt + 1 < NS/64) stageV(kt + 1);
    __syncthreads();                  // Vts(kt+1) ready
  }

  // epilogue -> cat[b][s][h0+hloc][d] bf16
  const int h = h0 + hloc;
  float inv[4];
#pragma unroll
  for (int r = 0; r < 4; r++) inv[r] = 1.f / lsum[r];
#pragma unroll
  for (int dt = 0; dt < 16; dt++) {
#pragma unroll
    for (int j = 0; j < 4; j++) {
      const int s = q0 + w*16 + l16*4 + j;
      const int d = dt*16 + l15;
      cat[((size_t)(b*NS + s)*8 + h)*256 + d] = f2b(o[dt][j] * inv[j]);
    }
  }
}

// ---------------- FC GEMM + bias + residual (writes f32 to d_out) -----------
__global__ void gemm_fc(const u16* __restrict__ cat, const u16* __restrict__ wfct,
                        const float* __restrict__ bfc, const float* __restrict__ x,
                        float* __restrict__ fcb) {
  __shared__ u16 As[128*32];
  __shared__ u16 Bs[64*32];
  const int tid = threadIdx.x;
  const int w = tid >> 6, l = tid & 63;
  const int wr = w >> 1, wc = w & 1;
  const int m0 = blockIdx.x * 128;
  const int n0 = blockIdx.y * 64;
  const int arow = tid >> 2;
  const int acol = (tid & 3) * 8;
  f32x4 acc[4][2] = {};
  for (int k0 = 0; k0 < 2048; k0 += 32) {
    __syncthreads();
#pragma unroll
    for (int i = 0; i < 2; i++)
      gl_lds16(cat + (size_t)(m0 + i*64 + arow)*2048 + k0 + acol, (char*)As + i*4096 + w*1024);
    gl_lds16(wfct + (size_t)(n0 + arow)*2048 + k0 + acol, (char*)Bs + w*1024);
    __syncthreads();
    bf16x8 af[4], bfr[2];
#pragma unroll
    for (int mt = 0; mt < 4; mt++)
      af[mt] = *(const bf16x8*)&As[(wr*64 + mt*16 + (l&15))*32 + (l>>4)*8];
#pragma unroll
    for (int nt = 0; nt < 2; nt++)
      bfr[nt] = *(const bf16x8*)&Bs[(wc*32 + nt*16 + (l&15))*32 + (l>>4)*8];
#pragma unroll
    for (int mt = 0; mt < 4; mt++)
#pragma unroll
      for (int nt = 0; nt < 2; nt++)
        acc[mt][nt] = __builtin_amdgcn_mfma_f32_16x16x32_bf16(af[mt], bfr[nt], acc[mt][nt], 0, 0, 0);
  }
#pragma unroll
  for (int mt = 0; mt < 4; mt++) {
#pragma unroll
    for (int nt = 0; nt < 2; nt++) {
      const int n = n0 + wc*32 + nt*16 + (l & 15);
      const float bias = bfc[n];
#pragma unroll
      for (int j = 0; j < 4; j++) {
        const int m = m0 + wr*64 + mt*16 + ((l>>4)<<2) + j;
        fcb[(size_t)m*256 + n] = acc[mt][nt][j] + bias + x[(size_t)m*256 + n];
      }
    }
  }
}

// ---------------- LayerNorm (in-place on d_out) -----------------------------
__global__ void ln_kernel(const float* __restrict__ fcb, const float* __restrict__ gamma,
                          const float* __restrict__ beta, float* __restrict__ out) {
  const int row = blockIdx.x * 4 + (threadIdx.x >> 6);
  const int l = threadIdx.x & 63;
  const float* r = fcb + (size_t)row * 256;
  f32x4 vv = *(const f32x4*)(r + l*4);
  float s  = vv[0] + vv[1] + vv[2] + vv[3];
  float s2 = vv[0]*vv[0] + vv[1]*vv[1] + vv[2]*vv[2] + vv[3]*vv[3];
#pragma unroll
  for (int mof = 1; mof <= 32; mof <<= 1) {
    s  += __shfl_xor(s, mof);
    s2 += __shfl_xor(s2, mof);
  }
  const float mu = s * (1.f/256.f);
  const float var = s2 * (1.f/256.f) - mu*mu;
  const float rs = rsqrtf(var + 1e-5f);
  f32x4 ov;
#pragma unroll
  for (int j = 0; j < 4; j++)
    ov[j] = (vv[j] - mu) * rs * gamma[l*4 + j] + beta[l*4 + j];
  *(f32x4*)(out + (size_t)row*256 + l*4) = ov;
}

// ---------------- launch ----------------------------------------------------
extern "C" void kernel_launch(void* const* d_in, const int* in_sizes, int n_in,
                              void* d_out, int out_size, void* d_ws, size_t ws_size,
                              hipStream_t stream) {
  (void)in_sizes; (void)n_in; (void)out_size;
  const float* x     = (const float*)d_in[0];
  const float* Wq    = (const float*)d_in[1];
  const float* bq    = (const float*)d_in[2];
  const float* Wk    = (const float*)d_in[3];
  const float* bk    = (const float*)d_in[4];
  const float* Wv    = (const float*)d_in[5];
  const float* bv    = (const float*)d_in[6];
  const float* Wfc   = (const float*)d_in[7];
  const float* bfc   = (const float*)d_in[8];
  const float* gamma = (const float*)d_in[9];
  const float* beta  = (const float*)d_in[10];
  float* out = (float*)d_out;

  // Head-group size chosen from ws_size (deterministic). Footprint 40+12*hg MiB.
  int hg, lg_hg;
  if      (ws_size >= (136ull << 20)) { hg = 8; lg_hg = 3; }
  else if (ws_size >= (88ull  << 20)) { hg = 4; lg_hg = 2; }
  else if (ws_size >= (64ull  << 20)) { hg = 2; lg_hg = 1; }
  else                                { hg = 1; lg_hg = 0; }

  char* ws = (char*)d_ws;
  u16*   xb   = (u16*)(ws);                               //  4 MiB x bf16 [8192][256]
  u16*   wt   = (u16*)(ws + (4ull<<20));                  //  3 MiB Wqkv^T bf16 [6144][256]
  u16*   wfct = (u16*)(ws + (7ull<<20));                  //  1 MiB Wfc^T bf16 [256][2048]
  const size_t grp = (size_t)hg << 22;                    //  4*hg MiB per q/k/v buffer
  u16*   qb   = (u16*)(ws + (8ull<<20));
  u16*   kb   = (u16*)(ws + (8ull<<20) + grp);
  u16*   vb   = (u16*)(ws + (8ull<<20) + 2*grp);
  u16*   catb = (u16*)(ws + (8ull<<20) + 3*grp);          // 32 MiB cat bf16 [8192][2048]

  prep_kernel<<<dim3(1024), dim3(256), 0, stream>>>(x, Wq, Wk, Wv, Wfc, xb, wt, wfct);
  for (int g = 0; g < NH / hg; g++) {
    const int h0 = g * hg;
    gemm_qkv<<<dim3(64, 6*hg), dim3(256), 0, stream>>>(xb, wt, bq, bk, bv, qb, kb, vb, h0, hg, lg_hg);
    attn_kernel<<<dim3(32, 4*hg), dim3(256), 0, stream>>>(qb, kb, vb, catb, h0, hg, lg_hg);
  }
  gemm_fc<<<dim3(64, 4), dim3(256), 0, stream>>>(catb, wfct, bfc, x, out);
  ln_kernel<<<dim3(2048), dim3(256), 0, stream>>>(out, gamma, beta, out);
}

// Round 7
// 382.040 us; speedup vs baseline: 2.5761x; 2.5761x over previous
//
#include <hip/hip_runtime.h>
#include <stdint.h>

typedef unsigned short u16;
typedef unsigned long long u64;
typedef __bf16 bf16x8 __attribute__((ext_vector_type(8)));
typedef float f32x4 __attribute__((ext_vector_type(4)));

#define NB 4
#define NS 2048
#define NC 256
#define NH 8
#define NM (NB*NS)        // 8192 rows (b,s)
#define NQKV (3*NH*NC)    // 6144
#define NHC (NH*NC)       // 2048

__device__ __forceinline__ u16 f2b(float f) {
  uint32_t u = __builtin_bit_cast(uint32_t, f);
  u += 0x7FFFu + ((u >> 16) & 1u);   // RNE
  return (u16)(u >> 16);
}
__device__ __forceinline__ float b2f(u16 h) {
  uint32_t u = ((uint32_t)h) << 16;
  return __builtin_bit_cast(float, u);
}
__device__ __forceinline__ void gl_lds16(const void* g, void* s) {
  __builtin_amdgcn_global_load_lds((const __attribute__((address_space(1))) void*)g,
                                   (__attribute__((address_space(3))) void*)s, 16, 0, 0);
}

// ---------------- prep: f32 -> bf16, weight transposes ----------------------
__global__ void prep_kernel(const float* __restrict__ x, const float* __restrict__ Wq,
                            const float* __restrict__ Wk, const float* __restrict__ Wv,
                            const float* __restrict__ Wfc,
                            u16* __restrict__ xb, u16* __restrict__ wt, u16* __restrict__ wfct) {
  const int total = NM*NC + NQKV*NC + NC*NHC;
  for (int i = blockIdx.x*blockDim.x + threadIdx.x; i < total; i += gridDim.x*blockDim.x) {
    if (i < NM*NC) {
      xb[i] = f2b(x[i]);
    } else if (i < NM*NC + NQKV*NC) {
      int j = i - NM*NC;              // j = n*256 + c ; n = proj*2048 + h*256 + d
      int n = j >> 8, c = j & 255;
      int proj = n >> 11, h = (n >> 8) & 7, d = n & 255;
      const float* W = (proj == 0) ? Wq : (proj == 1) ? Wk : Wv;
      wt[j] = f2b(W[((size_t)(h*NC + c))*NC + d]);     // wt[n][c] = W[h][c][d]
    } else {
      int j = i - NM*NC - NQKV*NC;    // j = d*2048 + jj
      int d = j >> 11, jj = j & 2047;
      wfct[j] = f2b(Wfc[(size_t)jj*NC + d]);           // wfct[d][jj] = Wfc[jj][d]
    }
  }
}

// ---------------- fused QKV projection GEMM (head-group aware) --------------
// Q/K scatter row-major to [b,hloc,s,d]; V scatters TILED-TRANSPOSED to
// [b,hloc][kt=s>>6][256 d][64 s&63]  (32KB contiguous per attn KV-tile).
__global__ void gemm_qkv(const u16* __restrict__ xb, const u16* __restrict__ wt,
                         const float* __restrict__ bq, const float* __restrict__ bk,
                         const float* __restrict__ bv,
                         u16* __restrict__ qo, u16* __restrict__ ko, u16* __restrict__ vo,
                         int h0, int hg, int lg_hg) {
  __shared__ u16 As[128*32];
  __shared__ u16 Bs[128*32];
  const int tid = threadIdx.x;
  const int w = tid >> 6, l = tid & 63;
  const int wr = w >> 1, wc = w & 1;
  const int m0 = blockIdx.x * 128;
  const int n0 = blockIdx.y * 128;             // within group N
  const int proj = n0 >> (8 + lg_hg);          // n0 / (hg*256)
  const int rem  = n0 & ((hg << 8) - 1);
  const int hloc = rem >> 8;
  const int dbase = rem & 255;                 // 0 or 128
  const int wrow0 = proj*2048 + ((h0 + hloc) << 8) + dbase;
  const int arow = tid >> 2;          // 0..63
  const int acol = (tid & 3) * 8;     // elems
  f32x4 acc[4][4] = {};
  for (int k0 = 0; k0 < 256; k0 += 32) {
    __syncthreads();
#pragma unroll
    for (int i = 0; i < 2; i++) {
      gl_lds16(xb + (size_t)(m0 + i*64 + arow)*256 + k0 + acol, (char*)As + i*4096 + w*1024);
      gl_lds16(wt + (size_t)(wrow0 + i*64 + arow)*256 + k0 + acol, (char*)Bs + i*4096 + w*1024);
    }
    __syncthreads();
    bf16x8 af[4], bfr[4];
#pragma unroll
    for (int mt = 0; mt < 4; mt++)
      af[mt] = *(const bf16x8*)&As[(wr*64 + mt*16 + (l&15))*32 + (l>>4)*8];
#pragma unroll
    for (int nt = 0; nt < 4; nt++)
      bfr[nt] = *(const bf16x8*)&Bs[(wc*64 + nt*16 + (l&15))*32 + (l>>4)*8];
#pragma unroll
    for (int mt = 0; mt < 4; mt++)
#pragma unroll
      for (int nt = 0; nt < 4; nt++)
        acc[mt][nt] = __builtin_amdgcn_mfma_f32_16x16x32_bf16(af[mt], bfr[nt], acc[mt][nt], 0, 0, 0);
  }
  if (proj == 2) {
    // V: +bias, ->bf16, tiled-transposed store (8B packed; s base mult of 4)
#pragma unroll
    for (int mt = 0; mt < 4; mt++) {
#pragma unroll
      for (int nt = 0; nt < 4; nt++) {
        const int dd = dbase + wc*64 + nt*16 + (l & 15);
        const float bb_ = bv[((h0 + hloc) << 8) + dd];
        const int m = m0 + wr*64 + mt*16 + ((l>>4)<<2);
        const int b = m >> 11, s = m & 2047;
        u16 pk[4];
#pragma unroll
        for (int j = 0; j < 4; j++) pk[j] = f2b(acc[mt][nt][j] + bb_);
        *(u64*)&vo[(size_t)(b*hg + hloc)*524288 + (size_t)(s>>6)*16384 + dd*64 + (s&63)]
            = *(const u64*)pk;
      }
    }
  } else {
    const float* bias = (proj == 0) ? bq : bk;
    u16* dst = (proj == 0) ? qo : ko;
#pragma unroll
    for (int mt = 0; mt < 4; mt++) {
#pragma unroll
      for (int nt = 0; nt < 4; nt++) {
        const int dd = dbase + wc*64 + nt*16 + (l & 15);
        const float bb_ = bias[((h0 + hloc) << 8) + dd];
#pragma unroll
        for (int j = 0; j < 4; j++) {
          const int m = m0 + wr*64 + mt*16 + ((l>>4)<<2) + j;
          const int b = m >> 11, s = m & 2047;
          dst[((size_t)((b*hg + hloc)*2048 + s))*256 + dd] = f2b(acc[mt][nt][j] + bb_);
        }
      }
    }
  }
}

// ---------------- flash attention (16 q/wave, 64 q/block; r2 compute) -------
// Ks [64 rows][32 granules], granule swizzled ^(row&7); Vts [256 d][8 granules]
// swizzled ^(d&7) — both staged by global_load_lds (linear LDS dest,
// pre-swizzled global source). Compute phase identical to round 2.
__global__ void __launch_bounds__(256, 2)
attn_kernel(const u16* __restrict__ q, const u16* __restrict__ k,
            const u16* __restrict__ vt, u16* __restrict__ cat,
            int h0, int hg, int lg_hg) {
  __shared__ u16 Ks[64*256];
  __shared__ u16 Vts[256*64];
  __shared__ u16 Ps[4][16*72];       // per-wave P scratch, pad 72 for bank spread
  const int tid = threadIdx.x;
  const int w = tid >> 6, l = tid & 63;
  const int l15 = l & 15, l16 = l >> 4, l7 = l & 7;
  const int bh = blockIdx.y;                   // b*hg + hloc
  const int b = bh >> lg_hg, hloc = bh & (hg - 1);
  const int q0 = blockIdx.x * 64;
  const u16* qp  = q  + (size_t)bh * NS * 256;
  const u16* kp  = k  + (size_t)bh * NS * 256;
  const u16* vtp = vt + (size_t)bh * 524288;

  // Q in registers: rows q0 + w*16 + l15, d = l16*8 + 32c
  bf16x8 qf[8];
  {
    const u16* qr = qp + (size_t)(q0 + w*16 + l15)*256 + l16*8;
#pragma unroll
    for (int c = 0; c < 8; c++) qf[c] = *(const bf16x8*)(qr + c*32);
  }
  f32x4 o[16];
#pragma unroll
  for (int i = 0; i < 16; i++) o[i] = f32x4{0.f, 0.f, 0.f, 0.f};
  float mrow[4], lsum[4];
#pragma unroll
  for (int r = 0; r < 4; r++) { mrow[r] = -1e30f; lsum[r] = 0.f; }
  const float sc = 0.0625f * 1.4426950408889634f;   // 1/sqrt(256) * log2(e)

  for (int kt = 0; kt < NS/64; kt++) {
    __syncthreads();
    // stage K tile (32KB) + V^T tile (32KB) via global_load_lds.
    // dest is linear; source granule pre-swizzled so LDS holds the
    // round-2 swizzled layouts (read code unchanged).
#pragma unroll
    for (int i = 0; i < 8; i++) {
      const int g = (w*8 + i)*64 + l;          // granule id 0..2047
      const int krow = g >> 5, kslot = g & 31;
      gl_lds16(kp + (size_t)(kt*64 + krow)*256 + ((kslot ^ (krow & 7)) << 3),
               (char*)Ks + (w*8 + i)*1024);
      const int vd = g >> 3, vslot = g & 7;
      gl_lds16(vtp + (size_t)kt*16384 + vd*64 + ((vslot ^ (vd & 7)) << 3),
               (char*)Vts + (w*8 + i)*1024);
    }
    __syncthreads();

    // QK^T: sacc[tt] = scores[q-rows l16*4+r][kcol l15+16tt]
    f32x4 sacc[4];
#pragma unroll
    for (int tt = 0; tt < 4; tt++) sacc[tt] = f32x4{0.f, 0.f, 0.f, 0.f};
#pragma unroll
    for (int ks = 0; ks < 8; ks++) {
#pragma unroll
      for (int tt = 0; tt < 4; tt++) {
        const int row = l15 + 16*tt;
        const bf16x8 kf = *(const bf16x8*)&Ks[row*256 + (((ks*4 + l16) ^ (row & 7)) << 3)];
        sacc[tt] = __builtin_amdgcn_mfma_f32_16x16x32_bf16(qf[ks], kf, sacc[tt], 0, 0, 0);
      }
    }

    // online softmax (base-2 domain); row-reduce = 4 shfl_xor in 16-lane group
    float pm[4];
#pragma unroll
    for (int r = 0; r < 4; r++)
      pm[r] = fmaxf(fmaxf(sacc[0][r], sacc[1][r]), fmaxf(sacc[2][r], sacc[3][r])) * sc;
#pragma unroll
    for (int mof = 1; mof <= 8; mof <<= 1)
#pragma unroll
      for (int r = 0; r < 4; r++)
        pm[r] = fmaxf(pm[r], __shfl_xor(pm[r], mof));
    float fr[4];
#pragma unroll
    for (int r = 0; r < 4; r++) {
      const float mn = fmaxf(mrow[r], pm[r]);
      fr[r] = exp2f(mrow[r] - mn);
      mrow[r] = mn;
    }
    float ps[4] = {0.f, 0.f, 0.f, 0.f};
#pragma unroll
    for (int tt = 0; tt < 4; tt++) {
#pragma unroll
      for (int r = 0; r < 4; r++) {
        const float p = exp2f(sacc[tt][r]*sc - mrow[r]);
        const u16 pb = f2b(p);
        ps[r] += b2f(pb);                 // sum what PV will actually use
        Ps[w][(l16*4 + r)*72 + l15 + 16*tt] = pb;
      }
    }
#pragma unroll
    for (int mof = 1; mof <= 8; mof <<= 1)
#pragma unroll
      for (int r = 0; r < 4; r++)
        ps[r] += __shfl_xor(ps[r], mof);
#pragma unroll
    for (int r = 0; r < 4; r++) lsum[r] = lsum[r]*fr[r] + ps[r];
#pragma unroll
    for (int dt = 0; dt < 16; dt++)
#pragma unroll
      for (int r = 0; r < 4; r++) o[dt][r] *= fr[r];

    // PV: o[dt] += P(16x64) * V^T-tile
    bf16x8 pa[2];
#pragma unroll
    for (int kk = 0; kk < 2; kk++)
      pa[kk] = *(const bf16x8*)&Ps[w][l15*72 + kk*32 + l16*8];
#pragma unroll
    for (int dt = 0; dt < 16; dt++) {
      const int dr = dt*16 + l15;
#pragma unroll
      for (int kk = 0; kk < 2; kk++) {
        const bf16x8 vf = *(const bf16x8*)&Vts[dr*64 + (((kk*4 + l16) ^ (dr & 7)) << 3)];
        o[dt] = __builtin_amdgcn_mfma_f32_16x16x32_bf16(pa[kk], vf, o[dt], 0, 0, 0);
      }
    }
  }
  // epilogue -> cat[b][s][h0+hloc][d] bf16
  const int h = h0 + hloc;
  float inv[4];
#pragma unroll
  for (int r = 0; r < 4; r++) inv[r] = 1.f / lsum[r];
#pragma unroll
  for (int dt = 0; dt < 16; dt++) {
#pragma unroll
    for (int j = 0; j < 4; j++) {
      const int s = q0 + w*16 + l16*4 + j;
      const int d = dt*16 + l15;
      cat[((size_t)(b*NS + s)*8 + h)*256 + d] = f2b(o[dt][j] * inv[j]);
    }
  }
}

// ---------------- FC GEMM + bias + residual (writes f32 to d_out) -----------
__global__ void gemm_fc(const u16* __restrict__ cat, const u16* __restrict__ wfct,
                        const float* __restrict__ bfc, const float* __restrict__ x,
                        float* __restrict__ fcb) {
  __shared__ u16 As[128*32];
  __shared__ u16 Bs[64*32];
  const int tid = threadIdx.x;
  const int w = tid >> 6, l = tid & 63;
  const int wr = w >> 1, wc = w & 1;
  const int m0 = blockIdx.x * 128;
  const int n0 = blockIdx.y * 64;
  const int arow = tid >> 2;
  const int acol = (tid & 3) * 8;
  f32x4 acc[4][2] = {};
  for (int k0 = 0; k0 < 2048; k0 += 32) {
    __syncthreads();
#pragma unroll
    for (int i = 0; i < 2; i++)
      gl_lds16(cat + (size_t)(m0 + i*64 + arow)*2048 + k0 + acol, (char*)As + i*4096 + w*1024);
    gl_lds16(wfct + (size_t)(n0 + arow)*2048 + k0 + acol, (char*)Bs + w*1024);
    __syncthreads();
    bf16x8 af[4], bfr[2];
#pragma unroll
    for (int mt = 0; mt < 4; mt++)
      af[mt] = *(const bf16x8*)&As[(wr*64 + mt*16 + (l&15))*32 + (l>>4)*8];
#pragma unroll
    for (int nt = 0; nt < 2; nt++)
      bfr[nt] = *(const bf16x8*)&Bs[(wc*32 + nt*16 + (l&15))*32 + (l>>4)*8];
#pragma unroll
    for (int mt = 0; mt < 4; mt++)
#pragma unroll
      for (int nt = 0; nt < 2; nt++)
        acc[mt][nt] = __builtin_amdgcn_mfma_f32_16x16x32_bf16(af[mt], bfr[nt], acc[mt][nt], 0, 0, 0);
  }
#pragma unroll
  for (int mt = 0; mt < 4; mt++) {
#pragma unroll
    for (int nt = 0; nt < 2; nt++) {
      const int n = n0 + wc*32 + nt*16 + (l & 15);
      const float bias = bfc[n];
#pragma unroll
      for (int j = 0; j < 4; j++) {
        const int m = m0 + wr*64 + mt*16 + ((l>>4)<<2) + j;
        fcb[(size_t)m*256 + n] = acc[mt][nt][j] + bias + x[(size_t)m*256 + n];
      }
    }
  }
}

// ---------------- LayerNorm (in-place on d_out) -----------------------------
__global__ void ln_kernel(const float* __restrict__ fcb, const float* __restrict__ gamma,
                          const float* __restrict__ beta, float* __restrict__ out) {
  const int row = blockIdx.x * 4 + (threadIdx.x >> 6);
  const int l = threadIdx.x & 63;
  const float* r = fcb + (size_t)row * 256;
  f32x4 vv = *(const f32x4*)(r + l*4);
  float s  = vv[0] + vv[1] + vv[2] + vv[3];
  float s2 = vv[0]*vv[0] + vv[1]*vv[1] + vv[2]*vv[2] + vv[3]*vv[3];
#pragma unroll
  for (int mof = 1; mof <= 32; mof <<= 1) {
    s  += __shfl_xor(s, mof);
    s2 += __shfl_xor(s2, mof);
  }
  const float mu = s * (1.f/256.f);
  const float var = s2 * (1.f/256.f) - mu*mu;
  const float rs = rsqrtf(var + 1e-5f);
  f32x4 ov;
#pragma unroll
  for (int j = 0; j < 4; j++)
    ov[j] = (vv[j] - mu) * rs * gamma[l*4 + j] + beta[l*4 + j];
  *(f32x4*)(out + (size_t)row*256 + l*4) = ov;
}

// ---------------- launch ----------------------------------------------------
extern "C" void kernel_launch(void* const* d_in, const int* in_sizes, int n_in,
                              void* d_out, int out_size, void* d_ws, size_t ws_size,
                              hipStream_t stream) {
  (void)in_sizes; (void)n_in; (void)out_size;
  const float* x     = (const float*)d_in[0];
  const float* Wq    = (const float*)d_in[1];
  const float* bq    = (const float*)d_in[2];
  const float* Wk    = (const float*)d_in[3];
  const float* bk    = (const float*)d_in[4];
  const float* Wv    = (const float*)d_in[5];
  const float* bv    = (const float*)d_in[6];
  const float* Wfc   = (const float*)d_in[7];
  const float* bfc   = (const float*)d_in[8];
  const float* gamma = (const float*)d_in[9];
  const float* beta  = (const float*)d_in[10];
  float* out = (float*)d_out;

  // Head-group size chosen from ws_size (deterministic). Footprint 40+12*hg MiB.
  int hg, lg_hg;
  if      (ws_size >= (136ull << 20)) { hg = 8; lg_hg = 3; }
  else if (ws_size >= (88ull  << 20)) { hg = 4; lg_hg = 2; }
  else if (ws_size >= (64ull  << 20)) { hg = 2; lg_hg = 1; }
  else                                { hg = 1; lg_hg = 0; }

  char* ws = (char*)d_ws;
  u16*   xb   = (u16*)(ws);                               //  4 MiB x bf16 [8192][256]
  u16*   wt   = (u16*)(ws + (4ull<<20));                  //  3 MiB Wqkv^T bf16 [6144][256]
  u16*   wfct = (u16*)(ws + (7ull<<20));                  //  1 MiB Wfc^T bf16 [256][2048]
  const size_t grp = (size_t)hg << 22;                    //  4*hg MiB per q/k/v buffer
  u16*   qb   = (u16*)(ws + (8ull<<20));
  u16*   kb   = (u16*)(ws + (8ull<<20) + grp);
  u16*   vb   = (u16*)(ws + (8ull<<20) + 2*grp);          // V tiled-transposed
  u16*   catb = (u16*)(ws + (8ull<<20) + 3*grp);          // 32 MiB cat bf16 [8192][2048]

  prep_kernel<<<dim3(1024), dim3(256), 0, stream>>>(x, Wq, Wk, Wv, Wfc, xb, wt, wfct);
  for (int g = 0; g < NH / hg; g++) {
    const int h0 = g * hg;
    gemm_qkv<<<dim3(64, 6*hg), dim3(256), 0, stream>>>(xb, wt, bq, bk, bv, qb, kb, vb, h0, hg, lg_hg);
    attn_kernel<<<dim3(32, 4*hg), dim3(256), 0, stream>>>(qb, kb, vb, catb, h0, hg, lg_hg);
  }
  gemm_fc<<<dim3(64, 4), dim3(256), 0, stream>>>(catb, wfct, bfc, x, out);
  ln_kernel<<<dim3(2048), dim3(256), 0, stream>>>(out, gamma, beta, out);
}